// Round 4
// baseline (526.058 us; speedup 1.0000x reference)
//
#include <hip/hip_runtime.h>
#include <hip/hip_bf16.h>
#include <cstdint>

#define IN_CH 128
#define HC    64
#define ED    16
#define SLOPE 0.2f

typedef float        f32x4 __attribute__((ext_vector_type(4)));
typedef unsigned int u32x4 __attribute__((ext_vector_type(4)));

// bf16 round-to-nearest-even pack/unpack
__device__ __forceinline__ uint32_t f2bf(float x) {
  uint32_t b = __float_as_uint(x);
  return (b + 0x7fffu + ((b >> 16) & 1u)) >> 16;
}
__device__ __forceinline__ float bf2f(uint32_t h) {
  return __uint_as_float(h << 16);
}

// ---------------- Kernel 1: h(bf16) = x@W, a_src, a_dst --------------------
__global__ __launch_bounds__(256) void k_node(
    const float* __restrict__ x, const float* __restrict__ W,
    const float* __restrict__ att_src_p, const float* __restrict__ att_dst_p,
    uint16_t* __restrict__ hb, float* __restrict__ a_src, float* __restrict__ a_dst,
    int N)
{
  int lane = threadIdx.x & 63;
  int gw = (blockIdx.x * blockDim.x + threadIdx.x) >> 6;
  int nwaves = (gridDim.x * blockDim.x) >> 6;
  float asv = att_src_p[lane];
  float adv = att_dst_p[lane];
  for (int n0 = gw * 4; n0 < N; n0 += nwaves * 4) {
    int n1 = min(n0 + 1, N - 1), n2 = min(n0 + 2, N - 1), n3 = min(n0 + 3, N - 1);
    const f32x4* xa = (const f32x4*)(x + (size_t)n0 * IN_CH);
    const f32x4* xb = (const f32x4*)(x + (size_t)n1 * IN_CH);
    const f32x4* xc = (const f32x4*)(x + (size_t)n2 * IN_CH);
    const f32x4* xd = (const f32x4*)(x + (size_t)n3 * IN_CH);
    float acc0 = 0.f, acc1 = 0.f, acc2 = 0.f, acc3 = 0.f;
#pragma unroll 4
    for (int k4 = 0; k4 < IN_CH / 4; k4++) {
      f32x4 va = __builtin_nontemporal_load(xa + k4);
      f32x4 vb = __builtin_nontemporal_load(xb + k4);
      f32x4 vc = __builtin_nontemporal_load(xc + k4);
      f32x4 vd = __builtin_nontemporal_load(xd + k4);
      float w0 = W[(k4 * 4 + 0) * HC + lane];
      float w1 = W[(k4 * 4 + 1) * HC + lane];
      float w2 = W[(k4 * 4 + 2) * HC + lane];
      float w3 = W[(k4 * 4 + 3) * HC + lane];
      acc0 += va.x * w0 + va.y * w1 + va.z * w2 + va.w * w3;
      acc1 += vb.x * w0 + vb.y * w1 + vb.z * w2 + vb.w * w3;
      acc2 += vc.x * w0 + vc.y * w1 + vc.z * w2 + vc.w * w3;
      acc3 += vd.x * w0 + vd.y * w1 + vd.z * w2 + vd.w * w3;
    }
    hb[(size_t)n0 * HC + lane] = (uint16_t)f2bf(acc0);
    if (n0 + 1 < N) hb[(size_t)n1 * HC + lane] = (uint16_t)f2bf(acc1);
    if (n0 + 2 < N) hb[(size_t)n2 * HC + lane] = (uint16_t)f2bf(acc2);
    if (n0 + 3 < N) hb[(size_t)n3 * HC + lane] = (uint16_t)f2bf(acc3);
    float s0 = acc0 * asv, s1 = acc1 * asv, s2 = acc2 * asv, s3 = acc3 * asv;
    float d0 = acc0 * adv, d1 = acc1 * adv, d2 = acc2 * adv, d3 = acc3 * adv;
#pragma unroll
    for (int m = 1; m < 16; m <<= 1) {
      s0 += __shfl_xor(s0, m); s1 += __shfl_xor(s1, m);
      s2 += __shfl_xor(s2, m); s3 += __shfl_xor(s3, m);
      d0 += __shfl_xor(d0, m); d1 += __shfl_xor(d1, m);
      d2 += __shfl_xor(d2, m); d3 += __shfl_xor(d3, m);
    }
    if ((lane & 15) == 0) {
      int hh = lane >> 4;
      a_src[(size_t)n0 * 4 + hh] = s0; a_dst[(size_t)n0 * 4 + hh] = d0;
      if (n0 + 1 < N) { a_src[(size_t)n1 * 4 + hh] = s1; a_dst[(size_t)n1 * 4 + hh] = d1; }
      if (n0 + 2 < N) { a_src[(size_t)n2 * 4 + hh] = s2; a_dst[(size_t)n2 * 4 + hh] = d2; }
      if (n0 + 3 < N) { a_src[(size_t)n3 * 4 + hh] = s3; a_dst[(size_t)n3 * 4 + hh] = d3; }
    }
  }
}

// ---------------- Kernel 2: degree histogram over dst ----------------------
__global__ __launch_bounds__(256) void k_hist(const int* __restrict__ dst, int E,
                                              int* __restrict__ deg)
{
  int e = blockIdx.x * 256 + threadIdx.x;
  if (e < E) atomicAdd(&deg[__builtin_nontemporal_load(dst + e)], 1);
}

// ---------------- Kernel 3a/3b/3c: exclusive scan -> rowptr + cursor -------
__global__ __launch_bounds__(256) void k_scan_a(const int* __restrict__ deg, int N,
                                                int* __restrict__ rowptr,
                                                int* __restrict__ blksums)
{
  __shared__ int tsum[256];
  int tid = threadIdx.x;
  int base = blockIdx.x * 2048 + tid * 8;
  int pre[8];
  int s = 0;
#pragma unroll
  for (int j = 0; j < 8; j++) {
    int idx = base + j;
    int v = (idx < N) ? deg[idx] : 0;
    pre[j] = s; s += v;
  }
  tsum[tid] = s;
  __syncthreads();
  for (int offm = 1; offm < 256; offm <<= 1) {
    int t = (tid >= offm) ? tsum[tid - offm] : 0;
    __syncthreads();
    tsum[tid] += t;
    __syncthreads();
  }
  int excl = tsum[tid] - s;
#pragma unroll
  for (int j = 0; j < 8; j++) {
    int idx = base + j;
    if (idx < N) rowptr[idx] = excl + pre[j];
  }
  if (tid == 255) blksums[blockIdx.x] = tsum[255];
}

__global__ void k_scan_b(int* __restrict__ blksums, int NB)
{
  if (threadIdx.x == 0 && blockIdx.x == 0) {
    int run = 0;
    for (int b = 0; b < NB; b++) { int t = blksums[b]; blksums[b] = run; run += t; }
  }
}

__global__ __launch_bounds__(256) void k_scan_c(int* __restrict__ rowptr,
                                                int* __restrict__ cursor,
                                                const int* __restrict__ blksums,
                                                int N, int E)
{
  int i = blockIdx.x * 256 + threadIdx.x;
  if (i < N) {
    int v = rowptr[i] + blksums[i >> 11];
    rowptr[i] = v;
    cursor[i] = v;             // k_edge's atomicAdd returns the slot directly
  }
  if (i == 0) rowptr[N] = E;
}

// ---------------- Kernel 4: edge logits + exp + packed 16B CSR scatter -----
__global__ __launch_bounds__(256) void k_edge4(
    const int* __restrict__ ei, const float* __restrict__ ea,
    const float* __restrict__ W_edge, const float* __restrict__ att_edge,
    const float* __restrict__ a_src, const float* __restrict__ a_dst,
    int* __restrict__ cursor, u32x4* __restrict__ pay, int E)
{
  __shared__ float ve[ED * 4];
  if (threadIdx.x < 64) {
    int d = threadIdx.x >> 2, hh = threadIdx.x & 3;
    float s = 0.f;
#pragma unroll
    for (int c = 0; c < 16; c++) s += W_edge[d * HC + hh * 16 + c] * att_edge[hh * 16 + c];
    ve[d * 4 + hh] = s;
  }
  __syncthreads();
  int e = blockIdx.x * 256 + threadIdx.x;
  if (e >= E) return;
  int sn = __builtin_nontemporal_load(ei + e);
  int dn = __builtin_nontemporal_load(ei + E + e);
  float4 as4 = *(const float4*)(a_src + (size_t)sn * 4);
  float4 ad4 = *(const float4*)(a_dst + (size_t)dn * 4);
  const f32x4* ea4 = (const f32x4*)(ea + (size_t)e * ED);
  f32x4 q0 = __builtin_nontemporal_load(ea4 + 0);
  f32x4 q1 = __builtin_nontemporal_load(ea4 + 1);
  f32x4 q2 = __builtin_nontemporal_load(ea4 + 2);
  f32x4 q3 = __builtin_nontemporal_load(ea4 + 3);
  float eav[16] = {q0.x,q0.y,q0.z,q0.w, q1.x,q1.y,q1.z,q1.w,
                   q2.x,q2.y,q2.z,q2.w, q3.x,q3.y,q3.z,q3.w};
  float ae0 = 0.f, ae1 = 0.f, ae2 = 0.f, ae3 = 0.f;
#pragma unroll
  for (int d = 0; d < ED; d++) {
    float v = eav[d];
    ae0 += v * ve[d * 4 + 0]; ae1 += v * ve[d * 4 + 1];
    ae2 += v * ve[d * 4 + 2]; ae3 += v * ve[d * 4 + 3];
  }
  float al0 = as4.x + ad4.x + ae0;
  float al1 = as4.y + ad4.y + ae1;
  float al2 = as4.z + ad4.z + ae2;
  float al3 = as4.w + ad4.w + ae3;
  al0 = al0 > 0.f ? al0 : SLOPE * al0;
  al1 = al1 > 0.f ? al1 : SLOPE * al1;
  al2 = al2 > 0.f ? al2 : SLOPE * al2;
  al3 = al3 > 0.f ? al3 : SLOPE * al3;
  int pos = atomicAdd(&cursor[dn], 1);
  u32x4 r;
  r.x = (uint32_t)sn;
  r.y = f2bf(__expf(al0)) | (f2bf(__expf(al1)) << 16);
  r.z = f2bf(__expf(al2)) | (f2bf(__expf(al3)) << 16);
  r.w = 0u;
  pay[pos] = r;   // regular store: want L2 allocation + sector combining
}

// ---------------- Kernel 5: per-node pull aggregation (4-deep ILP) ---------
__global__ __launch_bounds__(256) void k_agg4(
    const uint16_t* __restrict__ hb,
    const float* __restrict__ a_src, const float* __restrict__ a_dst,
    const float* __restrict__ W_edge, const float* __restrict__ att_edge,
    const float* __restrict__ bias, const int* __restrict__ rowptr,
    const u32x4* __restrict__ pay, float* __restrict__ out, int N)
{
  __shared__ float aes[4];
  if (threadIdx.x < 4) {
    int hh = threadIdx.x;
    float s = 0.f;
    for (int d = 0; d < ED; d++) {
      float vd = 0.f;
#pragma unroll
      for (int c = 0; c < 16; c++) vd += W_edge[d * HC + hh * 16 + c] * att_edge[hh * 16 + c];
      s += vd;
    }
    aes[hh] = s;
  }
  __syncthreads();
  int lane = threadIdx.x & 63;
  int n = blockIdx.x * 4 + (threadIdx.x >> 6);
  if (n >= N) return;
  int hq = lane >> 4;
  int b = rowptr[n], e = rowptr[n + 1];
  float acc = 0.f, den = 0.f;
  int p = b;
  for (; p + 3 < e; p += 4) {
    u32x4 r0 = __builtin_nontemporal_load(pay + p);
    u32x4 r1 = __builtin_nontemporal_load(pay + p + 1);
    u32x4 r2 = __builtin_nontemporal_load(pay + p + 2);
    u32x4 r3 = __builtin_nontemporal_load(pay + p + 3);
    uint32_t w0 = (hq & 2) ? r0.z : r0.y;
    uint32_t w1 = (hq & 2) ? r1.z : r1.y;
    uint32_t w2 = (hq & 2) ? r2.z : r2.y;
    uint32_t w3 = (hq & 2) ? r3.z : r3.y;
    float e0 = bf2f((hq & 1) ? (w0 >> 16) : (w0 & 0xffffu));
    float e1 = bf2f((hq & 1) ? (w1 >> 16) : (w1 & 0xffffu));
    float e2 = bf2f((hq & 1) ? (w2 >> 16) : (w2 & 0xffffu));
    float e3 = bf2f((hq & 1) ? (w3 >> 16) : (w3 & 0xffffu));
    float h0 = bf2f(hb[(size_t)r0.x * HC + lane]);
    float h1 = bf2f(hb[(size_t)r1.x * HC + lane]);
    float h2 = bf2f(hb[(size_t)r2.x * HC + lane]);
    float h3 = bf2f(hb[(size_t)r3.x * HC + lane]);
    acc += e0 * h0 + e1 * h1 + e2 * h2 + e3 * h3;
    den += (e0 + e1) + (e2 + e3);
  }
  for (; p < e; p++) {
    u32x4 r0 = __builtin_nontemporal_load(pay + p);
    uint32_t w0 = (hq & 2) ? r0.z : r0.y;
    float e0 = bf2f((hq & 1) ? (w0 >> 16) : (w0 & 0xffffu));
    acc += e0 * bf2f(hb[(size_t)r0.x * HC + lane]);
    den += e0;
  }
  // self loop (edge_attr filled with 1.0)
  float al = a_src[(size_t)n * 4 + hq] + a_dst[(size_t)n * 4 + hq] + aes[hq];
  al = al > 0.f ? al : SLOPE * al;
  float exs = __expf(al);
  acc += exs * bf2f(hb[(size_t)n * HC + lane]);
  den += exs;
  __builtin_nontemporal_store(acc / den + bias[lane], out + (size_t)n * HC + lane);
}

// ---------------- Launcher -------------------------------------------------
extern "C" void kernel_launch(void* const* d_in, const int* in_sizes, int n_in,
                              void* d_out, int out_size, void* d_ws, size_t ws_size,
                              hipStream_t stream)
{
  const float* x        = (const float*)d_in[0];
  const int*   ei       = (const int*)d_in[1];
  const float* ea       = (const float*)d_in[2];
  const float* W        = (const float*)d_in[3];
  const float* att_src  = (const float*)d_in[4];
  const float* att_dst  = (const float*)d_in[5];
  const float* W_edge   = (const float*)d_in[6];
  const float* att_edge = (const float*)d_in[7];
  const float* bias     = (const float*)d_in[8];
  float* out = (float*)d_out;

  int N = in_sizes[0] / IN_CH;
  int E = in_sizes[1] / 2;

  uint8_t* ws = (uint8_t*)d_ws;
  size_t off = 0;
  auto alloc = [&](size_t bytes) -> void* {
    void* p = ws + off;
    off = (off + bytes + 255) & ~(size_t)255;
    return p;
  };
  uint16_t* hb    = (uint16_t*)alloc((size_t)N * HC * 2);
  float* a_src_w  = (float*)alloc((size_t)N * 4 * 4);
  float* a_dst_w  = (float*)alloc((size_t)N * 4 * 4);
  int*   deg      = (int*)alloc((size_t)N * 4);
  int*   cursor   = (int*)alloc((size_t)N * 4);
  int*   rowptr   = (int*)alloc(((size_t)N + 1) * 4);
  int*   blksums  = (int*)alloc(64 * 4);
  u32x4* pay      = (u32x4*)alloc((size_t)E * 16);
  (void)ws_size; (void)n_in; (void)out_size;

  hipMemsetAsync(deg, 0, (size_t)N * 4, stream);

  k_node<<<512, 256, 0, stream>>>(x, W, att_src, att_dst, hb, a_src_w, a_dst_w, N);
  k_hist<<<(E + 255) / 256, 256, 0, stream>>>(ei + E, E, deg);
  int NB = (N + 2047) / 2048;
  k_scan_a<<<NB, 256, 0, stream>>>(deg, N, rowptr, blksums);
  k_scan_b<<<1, 64, 0, stream>>>(blksums, NB);
  k_scan_c<<<(N + 255) / 256, 256, 0, stream>>>(rowptr, cursor, blksums, N, E);
  k_edge4<<<(E + 255) / 256, 256, 0, stream>>>(ei, ea, W_edge, att_edge,
                                               a_src_w, a_dst_w, cursor, pay, E);
  k_agg4<<<(N + 3) / 4, 256, 0, stream>>>(hb, a_src_w, a_dst_w, W_edge, att_edge,
                                          bias, rowptr, pay, out, N);
}

// Round 5
// 509.957 us; speedup vs baseline: 1.0316x; 1.0316x over previous
//
#include <hip/hip_runtime.h>
#include <hip/hip_bf16.h>
#include <cstdint>

#define IN_CH 128
#define HC    64
#define ED    16
#define SLOPE 0.2f

typedef float        f32x4 __attribute__((ext_vector_type(4)));
typedef unsigned int u32x4 __attribute__((ext_vector_type(4)));

// bf16 round-to-nearest-even pack/unpack
__device__ __forceinline__ uint32_t f2bf(float x) {
  uint32_t b = __float_as_uint(x);
  return (b + 0x7fffu + ((b >> 16) & 1u)) >> 16;
}
__device__ __forceinline__ float bf2f(uint32_t h) {
  return __uint_as_float(h << 16);
}

// ---------------- Kernel 1: h(bf16) = x@W, a_src, a_dst --------------------
__global__ __launch_bounds__(256) void k_node(
    const float* __restrict__ x, const float* __restrict__ W,
    const float* __restrict__ att_src_p, const float* __restrict__ att_dst_p,
    uint16_t* __restrict__ hb, float* __restrict__ a_src, float* __restrict__ a_dst,
    int N)
{
  int lane = threadIdx.x & 63;
  int gw = (blockIdx.x * blockDim.x + threadIdx.x) >> 6;
  int nwaves = (gridDim.x * blockDim.x) >> 6;
  float asv = att_src_p[lane];
  float adv = att_dst_p[lane];
  for (int n0 = gw * 4; n0 < N; n0 += nwaves * 4) {
    int n1 = min(n0 + 1, N - 1), n2 = min(n0 + 2, N - 1), n3 = min(n0 + 3, N - 1);
    const f32x4* xa = (const f32x4*)(x + (size_t)n0 * IN_CH);
    const f32x4* xb = (const f32x4*)(x + (size_t)n1 * IN_CH);
    const f32x4* xc = (const f32x4*)(x + (size_t)n2 * IN_CH);
    const f32x4* xd = (const f32x4*)(x + (size_t)n3 * IN_CH);
    float acc0 = 0.f, acc1 = 0.f, acc2 = 0.f, acc3 = 0.f;
#pragma unroll 4
    for (int k4 = 0; k4 < IN_CH / 4; k4++) {
      f32x4 va = __builtin_nontemporal_load(xa + k4);
      f32x4 vb = __builtin_nontemporal_load(xb + k4);
      f32x4 vc = __builtin_nontemporal_load(xc + k4);
      f32x4 vd = __builtin_nontemporal_load(xd + k4);
      float w0 = W[(k4 * 4 + 0) * HC + lane];
      float w1 = W[(k4 * 4 + 1) * HC + lane];
      float w2 = W[(k4 * 4 + 2) * HC + lane];
      float w3 = W[(k4 * 4 + 3) * HC + lane];
      acc0 += va.x * w0 + va.y * w1 + va.z * w2 + va.w * w3;
      acc1 += vb.x * w0 + vb.y * w1 + vb.z * w2 + vb.w * w3;
      acc2 += vc.x * w0 + vc.y * w1 + vc.z * w2 + vc.w * w3;
      acc3 += vd.x * w0 + vd.y * w1 + vd.z * w2 + vd.w * w3;
    }
    hb[(size_t)n0 * HC + lane] = (uint16_t)f2bf(acc0);
    if (n0 + 1 < N) hb[(size_t)n1 * HC + lane] = (uint16_t)f2bf(acc1);
    if (n0 + 2 < N) hb[(size_t)n2 * HC + lane] = (uint16_t)f2bf(acc2);
    if (n0 + 3 < N) hb[(size_t)n3 * HC + lane] = (uint16_t)f2bf(acc3);
    float s0 = acc0 * asv, s1 = acc1 * asv, s2 = acc2 * asv, s3 = acc3 * asv;
    float d0 = acc0 * adv, d1 = acc1 * adv, d2 = acc2 * adv, d3 = acc3 * adv;
#pragma unroll
    for (int m = 1; m < 16; m <<= 1) {
      s0 += __shfl_xor(s0, m); s1 += __shfl_xor(s1, m);
      s2 += __shfl_xor(s2, m); s3 += __shfl_xor(s3, m);
      d0 += __shfl_xor(d0, m); d1 += __shfl_xor(d1, m);
      d2 += __shfl_xor(d2, m); d3 += __shfl_xor(d3, m);
    }
    if ((lane & 15) == 0) {
      int hh = lane >> 4;
      a_src[(size_t)n0 * 4 + hh] = s0; a_dst[(size_t)n0 * 4 + hh] = d0;
      if (n0 + 1 < N) { a_src[(size_t)n1 * 4 + hh] = s1; a_dst[(size_t)n1 * 4 + hh] = d1; }
      if (n0 + 2 < N) { a_src[(size_t)n2 * 4 + hh] = s2; a_dst[(size_t)n2 * 4 + hh] = d2; }
      if (n0 + 3 < N) { a_src[(size_t)n3 * 4 + hh] = s3; a_dst[(size_t)n3 * 4 + hh] = d3; }
    }
  }
}

// ---------------- Kernel 2: degree histogram over dst ----------------------
__global__ __launch_bounds__(256) void k_hist(const int* __restrict__ dst, int E,
                                              int* __restrict__ deg)
{
  int e = blockIdx.x * 256 + threadIdx.x;
  if (e < E) atomicAdd(&deg[__builtin_nontemporal_load(dst + e)], 1);
}

// ---------------- Kernel 3a/3b/3c: exclusive scan -> rowptr + cursor -------
__global__ __launch_bounds__(256) void k_scan_a(const int* __restrict__ deg, int N,
                                                int* __restrict__ rowptr,
                                                int* __restrict__ blksums)
{
  __shared__ int tsum[256];
  int tid = threadIdx.x;
  int base = blockIdx.x * 2048 + tid * 8;
  int pre[8];
  int s = 0;
#pragma unroll
  for (int j = 0; j < 8; j++) {
    int idx = base + j;
    int v = (idx < N) ? deg[idx] : 0;
    pre[j] = s; s += v;
  }
  tsum[tid] = s;
  __syncthreads();
  for (int offm = 1; offm < 256; offm <<= 1) {
    int t = (tid >= offm) ? tsum[tid - offm] : 0;
    __syncthreads();
    tsum[tid] += t;
    __syncthreads();
  }
  int excl = tsum[tid] - s;
#pragma unroll
  for (int j = 0; j < 8; j++) {
    int idx = base + j;
    if (idx < N) rowptr[idx] = excl + pre[j];
  }
  if (tid == 255) blksums[blockIdx.x] = tsum[255];
}

__global__ void k_scan_b(int* __restrict__ blksums, int NB)
{
  if (threadIdx.x == 0 && blockIdx.x == 0) {
    int run = 0;
    for (int b = 0; b < NB; b++) { int t = blksums[b]; blksums[b] = run; run += t; }
  }
}

__global__ __launch_bounds__(256) void k_scan_c(int* __restrict__ rowptr,
                                                int* __restrict__ cursor,
                                                const int* __restrict__ blksums,
                                                int N, int E)
{
  int i = blockIdx.x * 256 + threadIdx.x;
  if (i < N) {
    int v = rowptr[i] + blksums[i >> 11];
    rowptr[i] = v;
    cursor[i] = v;             // k_edge's atomicAdd returns the slot directly
  }
  if (i == 0) rowptr[N] = E;
}

// ---------------- Kernel 4: edge logits + exp + packed 16B CSR scatter -----
// payload: {x = sn*128 (byte offset into hb), y/z = exp(alpha) as 4xbf16, w=0}
__global__ __launch_bounds__(256) void k_edge5(
    const int* __restrict__ ei, const float* __restrict__ ea,
    const float* __restrict__ W_edge, const float* __restrict__ att_edge,
    const float* __restrict__ a_src, const float* __restrict__ a_dst,
    int* __restrict__ cursor, u32x4* __restrict__ pay, int E)
{
  __shared__ float ve[ED * 4];
  if (threadIdx.x < 64) {
    int d = threadIdx.x >> 2, hh = threadIdx.x & 3;
    float s = 0.f;
#pragma unroll
    for (int c = 0; c < 16; c++) s += W_edge[d * HC + hh * 16 + c] * att_edge[hh * 16 + c];
    ve[d * 4 + hh] = s;
  }
  __syncthreads();
  int e = blockIdx.x * 256 + threadIdx.x;
  if (e >= E) return;
  int sn = __builtin_nontemporal_load(ei + e);
  int dn = __builtin_nontemporal_load(ei + E + e);
  float4 as4 = *(const float4*)(a_src + (size_t)sn * 4);
  float4 ad4 = *(const float4*)(a_dst + (size_t)dn * 4);
  const f32x4* ea4 = (const f32x4*)(ea + (size_t)e * ED);
  f32x4 q0 = __builtin_nontemporal_load(ea4 + 0);
  f32x4 q1 = __builtin_nontemporal_load(ea4 + 1);
  f32x4 q2 = __builtin_nontemporal_load(ea4 + 2);
  f32x4 q3 = __builtin_nontemporal_load(ea4 + 3);
  float eav[16] = {q0.x,q0.y,q0.z,q0.w, q1.x,q1.y,q1.z,q1.w,
                   q2.x,q2.y,q2.z,q2.w, q3.x,q3.y,q3.z,q3.w};
  float ae0 = 0.f, ae1 = 0.f, ae2 = 0.f, ae3 = 0.f;
#pragma unroll
  for (int d = 0; d < ED; d++) {
    float v = eav[d];
    ae0 += v * ve[d * 4 + 0]; ae1 += v * ve[d * 4 + 1];
    ae2 += v * ve[d * 4 + 2]; ae3 += v * ve[d * 4 + 3];
  }
  float al0 = as4.x + ad4.x + ae0;
  float al1 = as4.y + ad4.y + ae1;
  float al2 = as4.z + ad4.z + ae2;
  float al3 = as4.w + ad4.w + ae3;
  al0 = al0 > 0.f ? al0 : SLOPE * al0;
  al1 = al1 > 0.f ? al1 : SLOPE * al1;
  al2 = al2 > 0.f ? al2 : SLOPE * al2;
  al3 = al3 > 0.f ? al3 : SLOPE * al3;
  int pos = atomicAdd(&cursor[dn], 1);
  u32x4 r;
  r.x = (uint32_t)sn * (HC * 2);     // byte offset into hb
  r.y = f2bf(__expf(al0)) | (f2bf(__expf(al1)) << 16);
  r.z = f2bf(__expf(al2)) | (f2bf(__expf(al3)) << 16);
  r.w = 0u;
  pay[pos] = r;   // plain store: L2 allocation + sector combining
}

// ---------------- Kernel 5: per-node pull aggregation (8-deep pipeline) ----
__global__ __launch_bounds__(256) void k_agg5(
    const uint16_t* __restrict__ hb,
    const float* __restrict__ a_src, const float* __restrict__ a_dst,
    const float* __restrict__ W_edge, const float* __restrict__ att_edge,
    const float* __restrict__ bias, const int* __restrict__ rowptr,
    const u32x4* __restrict__ pay, float* __restrict__ out, int N)
{
  __shared__ float aes[4];
  if (threadIdx.x < 4) {
    int hh = threadIdx.x;
    float s = 0.f;
    for (int d = 0; d < ED; d++) {
      float vd = 0.f;
#pragma unroll
      for (int c = 0; c < 16; c++) vd += W_edge[d * HC + hh * 16 + c] * att_edge[hh * 16 + c];
      s += vd;
    }
    aes[hh] = s;
  }
  __syncthreads();
  int lane = threadIdx.x & 63;
  int n = blockIdx.x * 4 + (threadIdx.x >> 6);
  if (n >= N) return;
  int hq = lane >> 4;
  bool selz = (hq & 2) != 0;     // pick r.z vs r.y
  bool selh = (hq & 1) != 0;     // pick high vs low bf16
  uint32_t lane2 = (uint32_t)lane * 2;
  const uint8_t* hbb = (const uint8_t*)hb;
  int b = rowptr[n], e = rowptr[n + 1];
  float acc = 0.f, den = 0.f;
  int p = b;
  for (; p + 7 < e; p += 8) {
    u32x4 r[8];
#pragma unroll
    for (int j = 0; j < 8; j++) r[j] = pay[p + j];   // wave-uniform
    float ee[8];
    uint32_t off[8];
#pragma unroll
    for (int j = 0; j < 8; j++) {
      uint32_t w = selz ? r[j].z : r[j].y;
      ee[j] = __uint_as_float(selh ? (w & 0xffff0000u) : (w << 16));
      off[j] = r[j].x + lane2;
    }
    float hv[8];
#pragma unroll
    for (int j = 0; j < 8; j++)
      hv[j] = bf2f(*(const uint16_t*)(hbb + off[j]));
#pragma unroll
    for (int j = 0; j < 8; j++) { acc += ee[j] * hv[j]; den += ee[j]; }
  }
  for (; p < e; p++) {
    u32x4 r0 = pay[p];
    uint32_t w = selz ? r0.z : r0.y;
    float e0 = __uint_as_float(selh ? (w & 0xffff0000u) : (w << 16));
    acc += e0 * bf2f(*(const uint16_t*)(hbb + r0.x + lane2));
    den += e0;
  }
  // self loop (edge_attr filled with 1.0)
  float al = a_src[(size_t)n * 4 + hq] + a_dst[(size_t)n * 4 + hq] + aes[hq];
  al = al > 0.f ? al : SLOPE * al;
  float exs = __expf(al);
  acc += exs * bf2f(*(const uint16_t*)(hbb + (uint32_t)n * (HC * 2) + lane2));
  den += exs;
  __builtin_nontemporal_store(acc / den + bias[lane], out + (size_t)n * HC + lane);
}

// ---------------- Launcher -------------------------------------------------
extern "C" void kernel_launch(void* const* d_in, const int* in_sizes, int n_in,
                              void* d_out, int out_size, void* d_ws, size_t ws_size,
                              hipStream_t stream)
{
  const float* x        = (const float*)d_in[0];
  const int*   ei       = (const int*)d_in[1];
  const float* ea       = (const float*)d_in[2];
  const float* W        = (const float*)d_in[3];
  const float* att_src  = (const float*)d_in[4];
  const float* att_dst  = (const float*)d_in[5];
  const float* W_edge   = (const float*)d_in[6];
  const float* att_edge = (const float*)d_in[7];
  const float* bias     = (const float*)d_in[8];
  float* out = (float*)d_out;

  int N = in_sizes[0] / IN_CH;
  int E = in_sizes[1] / 2;

  uint8_t* ws = (uint8_t*)d_ws;
  size_t off = 0;
  auto alloc = [&](size_t bytes) -> void* {
    void* p = ws + off;
    off = (off + bytes + 255) & ~(size_t)255;
    return p;
  };
  uint16_t* hb    = (uint16_t*)alloc((size_t)N * HC * 2);
  float* a_src_w  = (float*)alloc((size_t)N * 4 * 4);
  float* a_dst_w  = (float*)alloc((size_t)N * 4 * 4);
  int*   deg      = (int*)alloc((size_t)N * 4);
  int*   cursor   = (int*)alloc((size_t)N * 4);
  int*   rowptr   = (int*)alloc(((size_t)N + 1) * 4);
  int*   blksums  = (int*)alloc(64 * 4);
  u32x4* pay      = (u32x4*)alloc((size_t)E * 16);
  (void)ws_size; (void)n_in; (void)out_size;

  hipMemsetAsync(deg, 0, (size_t)N * 4, stream);

  k_node<<<512, 256, 0, stream>>>(x, W, att_src, att_dst, hb, a_src_w, a_dst_w, N);
  k_hist<<<(E + 255) / 256, 256, 0, stream>>>(ei + E, E, deg);
  int NB = (N + 2047) / 2048;
  k_scan_a<<<NB, 256, 0, stream>>>(deg, N, rowptr, blksums);
  k_scan_b<<<1, 64, 0, stream>>>(blksums, NB);
  k_scan_c<<<(N + 255) / 256, 256, 0, stream>>>(rowptr, cursor, blksums, N, E);
  k_edge5<<<(E + 255) / 256, 256, 0, stream>>>(ei, ea, W_edge, att_edge,
                                               a_src_w, a_dst_w, cursor, pay, E);
  k_agg5<<<(N + 3) / 4, 256, 0, stream>>>(hb, a_src_w, a_dst_w, W_edge, att_edge,
                                          bias, rowptr, pay, out, N);
}